// Round 11
// baseline (842.274 us; speedup 1.0000x reference)
//
#include <hip/hip_runtime.h>
#include <hip/hip_fp16.h>

#define DD  64
#define NSL 8      // channel slices (8 ch x bf16 = 16B each)
#define BKT 256    // dsts per coarse bucket
#define CAP 4608   // max edges/bucket (mean 4096, +8 sigma)

// ---------------- bf16 helpers (RTN-even) ----------------

__device__ __forceinline__ unsigned pk_bf16(float a, float b) {
    unsigned ua = __float_as_uint(a), ub = __float_as_uint(b);
    ua = (ua + 0x7fffu + ((ua >> 16) & 1u)) >> 16;
    ub = (ub + 0x7fffu + ((ub >> 16) & 1u)) & 0xffff0000u;
    return (ua & 0xffffu) | ub;
}
__device__ __forceinline__ void unpk_bf16(unsigned u, float& lo, float& hi) {
    lo = __uint_as_float(u << 16);
    hi = __uint_as_float(u & 0xffff0000u);
}

// ---------------- CSR build: 2-level bucket sort ----------------
// pass 1a: coarse histogram of dst>>8 (LDS-local, few global atomics)
__global__ __launch_bounds__(256) void p1hist_kernel(
    const int* __restrict__ ei, int* __restrict__ bh, int E, int NB)
{
    __shared__ int lh[256];
    lh[threadIdx.x] = 0;
    __syncthreads();
    for (int e = blockIdx.x * 256 + threadIdx.x; e < E; e += gridDim.x * 256)
        atomicAdd(&lh[ei[E + e] >> 8], 1);
    __syncthreads();
    if (threadIdx.x < NB && lh[threadIdx.x])
        atomicAdd(&bh[threadIdx.x], lh[threadIdx.x]);
}

// pass 1b: exclusive scan of NB (<=256) bucket counts -> bptr, bcur
__global__ __launch_bounds__(256) void p1scan_kernel(
    const int* __restrict__ bh, int* __restrict__ bptr, int* __restrict__ bcur,
    int NB, int E)
{
    __shared__ int s[256];
    int t = threadIdx.x;
    int v = (t < NB) ? bh[t] : 0;
    s[t] = v;
    __syncthreads();
    for (int off = 1; off < 256; off <<= 1) {
        int u = (t >= off) ? s[t - off] : 0;
        __syncthreads();
        s[t] += u;
        __syncthreads();
    }
    if (t < NB) { int ex = s[t] - v; bptr[t] = ex; bcur[t] = ex; }
    if (t == 0) bptr[NB] = E;
}

// pass 1c: scatter into coarse bucket streams. record = (src u16 | w fp16, dstlow)
__global__ __launch_bounds__(256) void p1fill_kernel(
    const int* __restrict__ ei, const float* __restrict__ ew,
    int* __restrict__ bcur, uint2* __restrict__ tmp, int E)
{
    int e = blockIdx.x * 256 + threadIdx.x;
    if (e >= E) return;
    int src = ei[e], dst = ei[E + e];
    unsigned short hw = __half_as_ushort(__float2half(ew[e]));
    unsigned lo = (unsigned)(unsigned short)src | ((unsigned)hw << 16);
    int pos = atomicAdd(&bcur[dst >> 8], 1);
    tmp[pos] = make_uint2(lo, (unsigned)(dst & 255));
}

// pass 2: per-bucket LDS counting sort -> final edges (4B records) + row_ptr
__global__ __launch_bounds__(1024) void p2sort_kernel(
    const uint2* __restrict__ tmp, const int* __restrict__ bptr,
    unsigned* __restrict__ edges, int* __restrict__ row_ptr,
    int N, int E, int NB)
{
    __shared__ int lh[BKT], lx[BKT], lc[BKT];
    __shared__ unsigned lout[CAP];
    int b = blockIdx.x;
    int base = bptr[b];
    int cnt = bptr[b + 1] - base;
    if (cnt > CAP) cnt = CAP;   // safety (prob. ~0 for this distribution)
    int t = threadIdx.x;
    if (t < BKT) lh[t] = 0;
    __syncthreads();
    for (int i = t; i < cnt; i += 1024)
        atomicAdd(&lh[tmp[base + i].y & 255], 1);
    __syncthreads();
    if (t < BKT) { lc[t] = lh[t]; lx[t] = lh[t]; }
    __syncthreads();
    for (int off = 1; off < BKT; off <<= 1) {
        int v = 0;
        if (t < BKT && t >= off) v = lx[t - off];
        __syncthreads();
        if (t < BKT && t >= off) lx[t] += v;
        __syncthreads();
    }
    if (t < BKT) { lx[t] -= lc[t]; lc[t] = 0; }   // lx = exclusive prefix
    __syncthreads();
    for (int i = t; i < cnt; i += 1024) {
        uint2 r = tmp[base + i];                  // L2 hit (2nd read)
        int dl = r.y & 255;
        int pos = lx[dl] + atomicAdd(&lc[dl], 1);
        lout[pos] = r.x;
    }
    __syncthreads();
    for (int i = t; i < cnt; i += 1024) edges[base + i] = lout[i];
    if (t < BKT) {
        int d = b * BKT + t;
        if (d < N) row_ptr[d] = base + lx[t];
    }
    if (b == NB - 1 && t == 0) row_ptr[N] = E;
}

// ---------------- quantize x -> slice-major bf16 T0 ----------------
// TT layout: [slice][node][8ch] ; slice = c8/8, 16B per (slice,node)
__global__ __launch_bounds__(256) void quantT_kernel(
    const float* __restrict__ x, unsigned short* __restrict__ T, int N)
{
    int n = blockIdx.x * 256 + threadIdx.x;
    int q = blockIdx.y;
    if (n >= N) return;
    const float* row = x + (size_t)n * DD + q * 8;
    float4 a = *reinterpret_cast<const float4*>(row);
    float4 b = *reinterpret_cast<const float4*>(row + 4);
    *reinterpret_cast<uint4*>(&T[((size_t)q * N + n) * 8]) =
        make_uint4(pk_bf16(a.x, a.y), pk_bf16(a.z, a.w),
                   pk_bf16(b.x, b.y), pk_bf16(b.z, b.w));
}

// ---------------- slice-pinned propagate ----------------
// slice = blockIdx % 8  -> (round-robin dispatch) XCD pin: slice table
// (0.8MB) stays resident in that XCD's L2. Wave = 4 nodes x 16 lanes, one
// edge/lane: 4B meta + 16B slice gather per edge. Xor-reduce masks 1/2/4/8.
// ALIASING: nextT may alias prevT (eidx==0 lane reads prev before write,
// same address, no other writer); must NOT alias hT.
__global__ __launch_bounds__(256) void prop_kernel(
    const unsigned short* __restrict__ hT, const unsigned short* __restrict__ prevT,
    const unsigned* __restrict__ edges, const int* __restrict__ row_ptr,
    unsigned short* __restrict__ nextT, int N)
{
    int slice = blockIdx.x & 7;
    int chunk = blockIdx.x >> 3;
    int lane  = threadIdx.x & 63;
    int wv    = threadIdx.x >> 6;
    int nodeloc = lane >> 4, eidx = lane & 15;
    int n = chunk * 16 + wv * 4 + nodeloc;
    if (n >= N) return;

    const unsigned short* sb = hT + (size_t)slice * N * 8;
    int beg = row_ptr[n], end = row_ptr[n + 1];

    float4 A0 = make_float4(0.f, 0.f, 0.f, 0.f), A1 = A0;
    for (int e = beg + eidx; e < end; e += 16) {
        unsigned rec = edges[e];
        float w = __half2float(__ushort_as_half((unsigned short)(rec >> 16)));
        const uint4 v = *reinterpret_cast<const uint4*>(
            &sb[(size_t)(rec & 0xffffu) * 8]);
        float lo, hi;
        unpk_bf16(v.x, lo, hi); A0.x = fmaf(w, lo, A0.x); A0.y = fmaf(w, hi, A0.y);
        unpk_bf16(v.y, lo, hi); A0.z = fmaf(w, lo, A0.z); A0.w = fmaf(w, hi, A0.w);
        unpk_bf16(v.z, lo, hi); A1.x = fmaf(w, lo, A1.x); A1.y = fmaf(w, hi, A1.y);
        unpk_bf16(v.w, lo, hi); A1.z = fmaf(w, lo, A1.z); A1.w = fmaf(w, hi, A1.w);
    }
#pragma unroll
    for (int mk = 1; mk <= 8; mk <<= 1) {
        A0.x += __shfl_xor(A0.x, mk); A0.y += __shfl_xor(A0.y, mk);
        A0.z += __shfl_xor(A0.z, mk); A0.w += __shfl_xor(A0.w, mk);
        A1.x += __shfl_xor(A1.x, mk); A1.y += __shfl_xor(A1.y, mk);
        A1.z += __shfl_xor(A1.z, mk); A1.w += __shfl_xor(A1.w, mk);
    }
    if (eidx == 0) {
        size_t off = ((size_t)slice * N + n) * 8;
        if (prevT) {
            uint4 p = *reinterpret_cast<const uint4*>(&prevT[off]);
            float lo, hi;
            unpk_bf16(p.x, lo, hi); A0.x = 2.f * A0.x - lo; A0.y = 2.f * A0.y - hi;
            unpk_bf16(p.y, lo, hi); A0.z = 2.f * A0.z - lo; A0.w = 2.f * A0.w - hi;
            unpk_bf16(p.z, lo, hi); A1.x = 2.f * A1.x - lo; A1.y = 2.f * A1.y - hi;
            unpk_bf16(p.w, lo, hi); A1.z = 2.f * A1.z - lo; A1.w = 2.f * A1.w - hi;
        }
        *reinterpret_cast<uint4*>(&nextT[off]) =
            make_uint4(pk_bf16(A0.x, A0.y), pk_bf16(A0.z, A0.w),
                       pk_bf16(A1.x, A1.y), pk_bf16(A1.z, A1.w));
    }
}

// ---------------- mega GEMM: out (+)= bias + sum_kc T{kc} @ W{kc} ----------
// Slice-major T input. Block 512 thr, 64 nodes; staging thread (q=tx>>6,
// nl=tx&63) reads 16B of slice q node nb0+nl -> contiguous 1KB/wave.
__global__ __launch_bounds__(512) void mega_gemm_kernel(
    const unsigned short* __restrict__ T0, const unsigned short* __restrict__ T1,
    const unsigned short* __restrict__ T2, const unsigned short* __restrict__ T3,
    const float* __restrict__ W, const float* __restrict__ bias,
    float* __restrict__ out, int N, int nord, int init)
{
    __shared__ float Ws[DD * DD];
    __shared__ float Ts[64][68];
    const unsigned short* Tl[4] = { T0, T1, T2, T3 };

    int nb0 = blockIdx.x * 64;
    int r = threadIdx.x >> 4, c = threadIdx.x & 15;
    int r2 = r * 2, c4 = c * 4;

    float acc[2][4];
    if (init) {
        const float4 bb = *reinterpret_cast<const float4*>(&bias[c4]);
#pragma unroll
        for (int i = 0; i < 2; ++i) {
            acc[i][0] = bb.x; acc[i][1] = bb.y; acc[i][2] = bb.z; acc[i][3] = bb.w;
        }
    } else {
#pragma unroll
        for (int i = 0; i < 2; ++i)
            acc[i][0] = acc[i][1] = acc[i][2] = acc[i][3] = 0.f;
    }

    int nl = threadIdx.x & 63, q = threadIdx.x >> 6;
    for (int kc = 0; kc < nord; ++kc) {
        __syncthreads();
        for (int i = threadIdx.x; i < DD * DD; i += 512)
            Ws[i] = W[kc * DD * DD + i];
        {
            uint4 u = make_uint4(0, 0, 0, 0);
            if (nb0 + nl < N)
                u = *reinterpret_cast<const uint4*>(
                    &Tl[kc][((size_t)q * N + nb0 + nl) * 8]);
            float f0, f1, f2, f3, f4, f5, f6, f7;
            unpk_bf16(u.x, f0, f1); unpk_bf16(u.y, f2, f3);
            unpk_bf16(u.z, f4, f5); unpk_bf16(u.w, f6, f7);
            *reinterpret_cast<float4*>(&Ts[nl][q * 8])     = make_float4(f0, f1, f2, f3);
            *reinterpret_cast<float4*>(&Ts[nl][q * 8 + 4]) = make_float4(f4, f5, f6, f7);
        }
        __syncthreads();
#pragma unroll 8
        for (int d = 0; d < DD; ++d) {
            float a0 = Ts[r2 + 0][d], a1 = Ts[r2 + 1][d];
            float4 b = *reinterpret_cast<const float4*>(&Ws[d * DD + c4]);
            acc[0][0] = fmaf(a0, b.x, acc[0][0]); acc[0][1] = fmaf(a0, b.y, acc[0][1]);
            acc[0][2] = fmaf(a0, b.z, acc[0][2]); acc[0][3] = fmaf(a0, b.w, acc[0][3]);
            acc[1][0] = fmaf(a1, b.x, acc[1][0]); acc[1][1] = fmaf(a1, b.y, acc[1][1]);
            acc[1][2] = fmaf(a1, b.z, acc[1][2]); acc[1][3] = fmaf(a1, b.w, acc[1][3]);
        }
    }

#pragma unroll
    for (int i = 0; i < 2; ++i) {
        int n = nb0 + r2 + i;
        if (n < N) {
            float4 o = make_float4(acc[i][0], acc[i][1], acc[i][2], acc[i][3]);
            if (!init) {
                float4 p = *reinterpret_cast<const float4*>(&out[(size_t)n * DD + c4]);
                o.x += p.x; o.y += p.y; o.z += p.z; o.w += p.w;
            }
            *reinterpret_cast<float4*>(&out[(size_t)n * DD + c4]) = o;
        }
    }
}

// ---------------- launch ----------------

static inline size_t rup(size_t x) { return (x + 255) & ~(size_t)255; }

extern "C" void kernel_launch(void* const* d_in, const int* in_sizes, int n_in,
                              void* d_out, int out_size, void* d_ws, size_t ws_size,
                              hipStream_t stream) {
    const float* x    = (const float*)d_in[0];
    const int*   ei   = (const int*)  d_in[1];
    const float* ew   = (const float*)d_in[2];
    const float* W    = (const float*)d_in[3];
    const float* bias = (const float*)d_in[4];
    float* out = (float*)d_out;

    int N = in_sizes[0] / DD;
    int E = in_sizes[2];
    int K = in_sizes[3] / (DD * DD);   // = 8
    int NB = (N + BKT - 1) / BKT;      // coarse buckets (<=256 needs N<=65536)

    size_t nb_bf = (size_t)N * DD * sizeof(unsigned short);

    // 5-buffer ring of slice-major T (k -> B[k%5]); tmp aliases B[1]
    // (consumed by p2sort before prop k=1 writes B[1] — stream-ordered).
    char* w = (char*)d_ws;
    unsigned short* B[5];
    for (int i = 0; i < 5; ++i) { B[i] = (unsigned short*)w; w += rup(nb_bf); }
    unsigned* edges  = (unsigned*)w;  w += rup((size_t)E * sizeof(unsigned));
    int* row_ptr = (int*)w;           w += rup((size_t)(N + 1) * sizeof(int));
    int* bh      = (int*)w;           w += rup((size_t)NB * sizeof(int));
    int* bptr    = (int*)w;           w += rup((size_t)(NB + 1) * sizeof(int));
    int* bcur    = (int*)w;           w += rup((size_t)NB * sizeof(int));
    uint2* tmp   = (uint2*)B[1];

    int eb   = (E + 255) / 256;
    int pb   = ((N + 15) / 16) * NSL;      // prop blocks: chunk-of-16 x 8 slices
    int gb64 = (N + 63) / 64;
    int qb   = (N + 255) / 256;

    // ---- CSR build (2-level bucket sort) ----
    hipMemsetAsync(bh, 0, (size_t)NB * sizeof(int), stream);
    p1hist_kernel<<<512, 256, 0, stream>>>(ei, bh, E, NB);
    p1scan_kernel<<<1, 256, 0, stream>>>(bh, bptr, bcur, NB, E);
    p1fill_kernel<<<eb, 256, 0, stream>>>(ei, ew, bcur, tmp, E);
    p2sort_kernel<<<NB, 1024, 0, stream>>>(tmp, bptr, edges, row_ptr, N, E, NB);

    // ---- T_0 = bf16(x), slice-major ----
    quantT_kernel<<<dim3(qb, NSL), 256, 0, stream>>>(x, B[0], N);

    // ---- recursion + chunked deferred GEMM ----
    int done = 0;
    for (int k = 1; k < K; ++k) {
        const unsigned short* cur  = B[(k - 1) % 5];
        const unsigned short* prev = (k >= 2) ? B[(k - 2) % 5] : nullptr;
        unsigned short*       nxt  = B[k % 5];
        prop_kernel<<<pb, 256, 0, stream>>>(cur, prev, edges, row_ptr, nxt, N);
        if (k % 4 == 3) {
            int c0 = done;
            mega_gemm_kernel<<<gb64, 512, 0, stream>>>(
                B[(c0 + 0) % 5], B[(c0 + 1) % 5], B[(c0 + 2) % 5], B[(c0 + 3) % 5],
                W + (size_t)c0 * DD * DD, bias, out, N, 4, done == 0);
            done += 4;
        }
    }
    if (done < K) {
        mega_gemm_kernel<<<gb64, 512, 0, stream>>>(
            B[(done + 0) % 5], B[(done + 1) % 5],
            B[(done + 2) % 5], B[(done + 3) % 5],
            W + (size_t)done * DD * DD, bias, out, N, K - done, done == 0);
    }
}

// Round 12
// 465.670 us; speedup vs baseline: 1.8087x; 1.8087x over previous
//
#include <hip/hip_runtime.h>
#include <hip/hip_fp16.h>

#define DD  64
#define NSL 8      // channel slices (8 ch x bf16 = 16B each)

// ---------------- bf16 helpers (RTN-even) ----------------

__device__ __forceinline__ unsigned pk_bf16(float a, float b) {
    unsigned ua = __float_as_uint(a), ub = __float_as_uint(b);
    ua = (ua + 0x7fffu + ((ua >> 16) & 1u)) >> 16;
    ub = (ub + 0x7fffu + ((ub >> 16) & 1u)) & 0xffff0000u;
    return (ua & 0xffffu) | ub;
}
__device__ __forceinline__ void unpk_bf16(unsigned u, float& lo, float& hi) {
    lo = __uint_as_float(u << 16);
    hi = __uint_as_float(u & 0xffff0000u);
}

// ---------------- CSR build (round-10 style: 50k cursors) ----------------

__global__ __launch_bounds__(256) void hist_kernel(
    const int* __restrict__ ei, int* __restrict__ cnt, int E)
{
    int e = blockIdx.x * 256 + threadIdx.x;
    if (e < E) atomicAdd(&cnt[ei[E + e]], 1);
}

__global__ __launch_bounds__(256) void scanA_kernel(
    const int* __restrict__ cnt, int* __restrict__ bsum, int N)
{
    __shared__ int s[256];
    int idx = blockIdx.x * 256 + threadIdx.x;
    s[threadIdx.x] = (idx < N) ? cnt[idx] : 0;
    __syncthreads();
    for (int off = 128; off > 0; off >>= 1) {
        if (threadIdx.x < off) s[threadIdx.x] += s[threadIdx.x + off];
        __syncthreads();
    }
    if (threadIdx.x == 0) bsum[blockIdx.x] = s[0];
}

__global__ __launch_bounds__(256) void scanB_kernel(int* __restrict__ bsum, int nb)
{
    __shared__ int s[256];
    int carry = 0;
    for (int base = 0; base < nb; base += 256) {
        int i = base + threadIdx.x;
        int v = (i < nb) ? bsum[i] : 0;
        s[threadIdx.x] = v;
        __syncthreads();
        for (int off = 1; off < 256; off <<= 1) {
            int t = (threadIdx.x >= off) ? s[threadIdx.x - off] : 0;
            __syncthreads();
            s[threadIdx.x] += t;
            __syncthreads();
        }
        if (i < nb) bsum[i] = carry + s[threadIdx.x] - v;   // exclusive
        int tot = s[255];
        __syncthreads();
        carry += tot;
    }
}

__global__ __launch_bounds__(256) void scanC_kernel(
    const int* __restrict__ cnt, const int* __restrict__ bsum,
    int* __restrict__ row_ptr, int N, int E)
{
    __shared__ int s[256];
    int idx = blockIdx.x * 256 + threadIdx.x;
    int v = (idx < N) ? cnt[idx] : 0;
    s[threadIdx.x] = v;
    __syncthreads();
    for (int off = 1; off < 256; off <<= 1) {
        int t = (threadIdx.x >= off) ? s[threadIdx.x - off] : 0;
        __syncthreads();
        s[threadIdx.x] += t;
        __syncthreads();
    }
    if (idx < N) row_ptr[idx] = s[threadIdx.x] - v + bsum[blockIdx.x];
    if (idx == N) row_ptr[N] = E;
}

// scatter edges into CSR slots: 4B record = src u16 | w fp16
__global__ __launch_bounds__(256) void fill_kernel(
    const int* __restrict__ ei, const float* __restrict__ ew,
    int* __restrict__ cursor, unsigned* __restrict__ edges, int E)
{
    int e = blockIdx.x * 256 + threadIdx.x;
    if (e >= E) return;
    int src = ei[e], dst = ei[E + e];
    unsigned short hw = __half_as_ushort(__float2half(ew[e]));
    int pos = atomicAdd(&cursor[dst], 1);
    edges[pos] = (unsigned)(unsigned short)src | ((unsigned)hw << 16);
}

// ---------------- quantize x -> slice-major bf16 T0 ----------------
// T layout: [slice][node][8ch], 16B per (slice,node)
__global__ __launch_bounds__(256) void quantT_kernel(
    const float* __restrict__ x, unsigned short* __restrict__ T, int N)
{
    int n = blockIdx.x * 256 + threadIdx.x;
    int q = blockIdx.y;
    if (n >= N) return;
    const float* row = x + (size_t)n * DD + q * 8;
    float4 a = *reinterpret_cast<const float4*>(row);
    float4 b = *reinterpret_cast<const float4*>(row + 4);
    *reinterpret_cast<uint4*>(&T[((size_t)q * N + n) * 8]) =
        make_uint4(pk_bf16(a.x, a.y), pk_bf16(a.z, a.w),
                   pk_bf16(b.x, b.y), pk_bf16(b.z, b.w));
}

// ---------------- slice-pinned propagate ----------------
// slice = blockIdx % 8 -> round-robin dispatch pins each 0.8MB slice table
// to one XCD's L2. Wave = 4 nodes x 16 lanes, one edge/lane: 4B meta + 16B
// slice gather per edge. Xor-reduce masks 1/2/4/8.
// ALIASING: nextT may alias prevT (eidx==0 lane reads prev before writing
// same address; no other writer); must NOT alias hT.
__global__ __launch_bounds__(256) void prop_kernel(
    const unsigned short* __restrict__ hT, const unsigned short* __restrict__ prevT,
    const unsigned* __restrict__ edges, const int* __restrict__ row_ptr,
    unsigned short* __restrict__ nextT, int N)
{
    int slice = blockIdx.x & 7;
    int chunk = blockIdx.x >> 3;
    int lane  = threadIdx.x & 63;
    int wv    = threadIdx.x >> 6;
    int nodeloc = lane >> 4, eidx = lane & 15;
    int n = chunk * 16 + wv * 4 + nodeloc;
    if (n >= N) return;

    const unsigned short* sb = hT + (size_t)slice * N * 8;
    int beg = row_ptr[n], end = row_ptr[n + 1];

    float4 A0 = make_float4(0.f, 0.f, 0.f, 0.f), A1 = A0;
    for (int e = beg + eidx; e < end; e += 16) {
        unsigned rec = edges[e];
        float w = __half2float(__ushort_as_half((unsigned short)(rec >> 16)));
        const uint4 v = *reinterpret_cast<const uint4*>(
            &sb[(size_t)(rec & 0xffffu) * 8]);
        float lo, hi;
        unpk_bf16(v.x, lo, hi); A0.x = fmaf(w, lo, A0.x); A0.y = fmaf(w, hi, A0.y);
        unpk_bf16(v.y, lo, hi); A0.z = fmaf(w, lo, A0.z); A0.w = fmaf(w, hi, A0.w);
        unpk_bf16(v.z, lo, hi); A1.x = fmaf(w, lo, A1.x); A1.y = fmaf(w, hi, A1.y);
        unpk_bf16(v.w, lo, hi); A1.z = fmaf(w, lo, A1.z); A1.w = fmaf(w, hi, A1.w);
    }
#pragma unroll
    for (int mk = 1; mk <= 8; mk <<= 1) {
        A0.x += __shfl_xor(A0.x, mk); A0.y += __shfl_xor(A0.y, mk);
        A0.z += __shfl_xor(A0.z, mk); A0.w += __shfl_xor(A0.w, mk);
        A1.x += __shfl_xor(A1.x, mk); A1.y += __shfl_xor(A1.y, mk);
        A1.z += __shfl_xor(A1.z, mk); A1.w += __shfl_xor(A1.w, mk);
    }
    if (eidx == 0) {
        size_t off = ((size_t)slice * N + n) * 8;
        if (prevT) {
            uint4 p = *reinterpret_cast<const uint4*>(&prevT[off]);
            float lo, hi;
            unpk_bf16(p.x, lo, hi); A0.x = 2.f * A0.x - lo; A0.y = 2.f * A0.y - hi;
            unpk_bf16(p.y, lo, hi); A0.z = 2.f * A0.z - lo; A0.w = 2.f * A0.w - hi;
            unpk_bf16(p.z, lo, hi); A1.x = 2.f * A1.x - lo; A1.y = 2.f * A1.y - hi;
            unpk_bf16(p.w, lo, hi); A1.z = 2.f * A1.z - lo; A1.w = 2.f * A1.w - hi;
        }
        *reinterpret_cast<uint4*>(&nextT[off]) =
            make_uint4(pk_bf16(A0.x, A0.y), pk_bf16(A0.z, A0.w),
                       pk_bf16(A1.x, A1.y), pk_bf16(A1.z, A1.w));
    }
}

// ---------------- mega GEMM: out (+)= bias + sum_kc T{kc} @ W{kc} ----------
__global__ __launch_bounds__(512) void mega_gemm_kernel(
    const unsigned short* __restrict__ T0, const unsigned short* __restrict__ T1,
    const unsigned short* __restrict__ T2, const unsigned short* __restrict__ T3,
    const float* __restrict__ W, const float* __restrict__ bias,
    float* __restrict__ out, int N, int nord, int init)
{
    __shared__ float Ws[DD * DD];
    __shared__ float Ts[64][68];
    const unsigned short* Tl[4] = { T0, T1, T2, T3 };

    int nb0 = blockIdx.x * 64;
    int r = threadIdx.x >> 4, c = threadIdx.x & 15;
    int r2 = r * 2, c4 = c * 4;

    float acc[2][4];
    if (init) {
        const float4 bb = *reinterpret_cast<const float4*>(&bias[c4]);
#pragma unroll
        for (int i = 0; i < 2; ++i) {
            acc[i][0] = bb.x; acc[i][1] = bb.y; acc[i][2] = bb.z; acc[i][3] = bb.w;
        }
    } else {
#pragma unroll
        for (int i = 0; i < 2; ++i)
            acc[i][0] = acc[i][1] = acc[i][2] = acc[i][3] = 0.f;
    }

    int nl = threadIdx.x & 63, q = threadIdx.x >> 6;
    for (int kc = 0; kc < nord; ++kc) {
        __syncthreads();
        for (int i = threadIdx.x; i < DD * DD; i += 512)
            Ws[i] = W[kc * DD * DD + i];
        {
            uint4 u = make_uint4(0, 0, 0, 0);
            if (nb0 + nl < N)
                u = *reinterpret_cast<const uint4*>(
                    &Tl[kc][((size_t)q * N + nb0 + nl) * 8]);
            float f0, f1, f2, f3, f4, f5, f6, f7;
            unpk_bf16(u.x, f0, f1); unpk_bf16(u.y, f2, f3);
            unpk_bf16(u.z, f4, f5); unpk_bf16(u.w, f6, f7);
            *reinterpret_cast<float4*>(&Ts[nl][q * 8])     = make_float4(f0, f1, f2, f3);
            *reinterpret_cast<float4*>(&Ts[nl][q * 8 + 4]) = make_float4(f4, f5, f6, f7);
        }
        __syncthreads();
#pragma unroll 8
        for (int d = 0; d < DD; ++d) {
            float a0 = Ts[r2 + 0][d], a1 = Ts[r2 + 1][d];
            float4 b = *reinterpret_cast<const float4*>(&Ws[d * DD + c4]);
            acc[0][0] = fmaf(a0, b.x, acc[0][0]); acc[0][1] = fmaf(a0, b.y, acc[0][1]);
            acc[0][2] = fmaf(a0, b.z, acc[0][2]); acc[0][3] = fmaf(a0, b.w, acc[0][3]);
            acc[1][0] = fmaf(a1, b.x, acc[1][0]); acc[1][1] = fmaf(a1, b.y, acc[1][1]);
            acc[1][2] = fmaf(a1, b.z, acc[1][2]); acc[1][3] = fmaf(a1, b.w, acc[1][3]);
        }
    }

#pragma unroll
    for (int i = 0; i < 2; ++i) {
        int n = nb0 + r2 + i;
        if (n < N) {
            float4 o = make_float4(acc[i][0], acc[i][1], acc[i][2], acc[i][3]);
            if (!init) {
                float4 p = *reinterpret_cast<const float4*>(&out[(size_t)n * DD + c4]);
                o.x += p.x; o.y += p.y; o.z += p.z; o.w += p.w;
            }
            *reinterpret_cast<float4*>(&out[(size_t)n * DD + c4]) = o;
        }
    }
}

// ---------------- launch ----------------

static inline size_t rup(size_t x) { return (x + 255) & ~(size_t)255; }

extern "C" void kernel_launch(void* const* d_in, const int* in_sizes, int n_in,
                              void* d_out, int out_size, void* d_ws, size_t ws_size,
                              hipStream_t stream) {
    const float* x    = (const float*)d_in[0];
    const int*   ei   = (const int*)  d_in[1];
    const float* ew   = (const float*)d_in[2];
    const float* W    = (const float*)d_in[3];
    const float* bias = (const float*)d_in[4];
    float* out = (float*)d_out;

    int N = in_sizes[0] / DD;
    int E = in_sizes[2];
    int K = in_sizes[3] / (DD * DD);   // = 8

    size_t nb_bf = (size_t)N * DD * sizeof(unsigned short);
    int nb_scan = (N + 1 + 255) / 256;

    // 5-buffer ring of slice-major T (k -> B[k%5])
    char* w = (char*)d_ws;
    unsigned short* B[5];
    for (int i = 0; i < 5; ++i) { B[i] = (unsigned short*)w; w += rup(nb_bf); }
    unsigned* edges  = (unsigned*)w;  w += rup((size_t)E * sizeof(unsigned));
    int* cnt     = (int*)w;           w += rup((size_t)N * sizeof(int));
    int* row_ptr = (int*)w;           w += rup((size_t)(N + 1) * sizeof(int));
    int* bsum    = (int*)w;           w += rup((size_t)nb_scan * sizeof(int));

    int eb   = (E + 255) / 256;
    int pb   = ((N + 15) / 16) * NSL;      // prop blocks: chunk-of-16 x 8 slices
    int gb64 = (N + 63) / 64;
    int qb   = (N + 255) / 256;

    // ---- CSR build (50k-cursor counting sort: round-10 proven) ----
    hipMemsetAsync(cnt, 0, (size_t)N * sizeof(int), stream);
    hist_kernel<<<eb, 256, 0, stream>>>(ei, cnt, E);
    scanA_kernel<<<nb_scan, 256, 0, stream>>>(cnt, bsum, N);
    scanB_kernel<<<1, 256, 0, stream>>>(bsum, nb_scan);
    scanC_kernel<<<nb_scan, 256, 0, stream>>>(cnt, bsum, row_ptr, N, E);
    hipMemcpyAsync(cnt, row_ptr, (size_t)N * sizeof(int),
                   hipMemcpyDeviceToDevice, stream);           // cnt -> cursor
    fill_kernel<<<eb, 256, 0, stream>>>(ei, ew, cnt, edges, E);

    // ---- T_0 = bf16(x), slice-major ----
    quantT_kernel<<<dim3(qb, NSL), 256, 0, stream>>>(x, B[0], N);

    // ---- recursion + chunked deferred GEMM ----
    int done = 0;
    for (int k = 1; k < K; ++k) {
        const unsigned short* cur  = B[(k - 1) % 5];
        const unsigned short* prev = (k >= 2) ? B[(k - 2) % 5] : nullptr;
        unsigned short*       nxt  = B[k % 5];
        prop_kernel<<<pb, 256, 0, stream>>>(cur, prev, edges, row_ptr, nxt, N);
        if (k % 4 == 3) {
            int c0 = done;
            mega_gemm_kernel<<<gb64, 512, 0, stream>>>(
                B[(c0 + 0) % 5], B[(c0 + 1) % 5], B[(c0 + 2) % 5], B[(c0 + 3) % 5],
                W + (size_t)c0 * DD * DD, bias, out, N, 4, done == 0);
            done += 4;
        }
    }
    if (done < K) {
        mega_gemm_kernel<<<gb64, 512, 0, stream>>>(
            B[(done + 0) % 5], B[(done + 1) % 5],
            B[(done + 2) % 5], B[(done + 3) % 5],
            W + (size_t)done * DD * DD, bias, out, N, K - done, done == 0);
    }
}